// Round 3
// baseline (221429.224 us; speedup 1.0000x reference)
//
#include <hip/hip_runtime.h>
#include <stdint.h>

typedef __bf16 bf16;
typedef __bf16 bf16x8 __attribute__((ext_vector_type(8)));
typedef float f32x4 __attribute__((ext_vector_type(4)));

// ---------------------------------------------------------------------------
// Weight pre-pack: f32 [N,K] row-major -> split hi/lo bf16 in MFMA B-frag
// streaming layout: pk[half][nf][ks][lane][8],  lane = (n&15) | (((k&31)>>3)<<4),
// ks = k>>5, e = k&7.  One 16B load per (lane, nf, ks, half), fully coalesced.
// ---------------------------------------------------------------------------
__global__ void pack_split(const float* __restrict__ src, bf16* __restrict__ dst,
                           int N, int K, int NFtot, int nfBase)
{
    int gid = blockIdx.x * 256 + threadIdx.x;
    if (gid >= N * K) return;
    int n = gid / K, k = gid - n * K;
    int KS = K >> 5;
    float x = src[gid];
    bf16 hb = (bf16)x;                    // RNE
    bf16 lb = (bf16)(x - (float)hb);      // residual (exact in f32)
    int nf = nfBase + (n >> 4);
    int l  = (n & 15) | (((k & 31) >> 3) << 4);
    int ks = k >> 5;
    int e  = k & 7;
    int base = ((nf * KS + ks) << 9) + (l << 3) + e;
    int half = NFtot * KS * 512;
    dst[base] = hb;
    dst[half + base] = lb;
}

// ---------------------------------------------------------------------------
// Deep-pipelined streamed split-bf16 MFMA.
// acc[i] = A(16xK from LDS S) @ W(cols of frag nf0+i)^T, 3-term split
// (hi*hi + lo*hi + hi*lo), f32 accumulate. Rotating DEPTH-slot prefetch
// buffers keep NFR*2*DEPTH 16-B global loads in flight.
// S layout: [half][ks][lane][8] bf16 (half stride 8192 elems).
// ---------------------------------------------------------------------------
template<int NFR, int KS, int DEPTH>
__device__ __forceinline__ void mm_deep(const bf16* __restrict__ pk, int halfelems,
                                        int nf0, int lane,
                                        const bf16* __restrict__ S, f32x4* acc)
{
    bf16x8 bh[DEPTH][NFR], bl[DEPTH][NFR];
    const bf16* base = pk + ((nf0 * KS) << 9) + (lane << 3);
#pragma unroll
    for (int p = 0; p < DEPTH; ++p)
#pragma unroll
        for (int i = 0; i < NFR; ++i) {
            bh[p][i] = *(const bf16x8*)(base + ((i * KS + p) << 9));
            bl[p][i] = *(const bf16x8*)(base + halfelems + ((i * KS + p) << 9));
        }
#pragma unroll
    for (int i = 0; i < NFR; ++i) { f32x4 z = {0.f, 0.f, 0.f, 0.f}; acc[i] = z; }
#pragma unroll
    for (int ks = 0; ks < KS; ++ks) {
        const int slot = ks % DEPTH;
        bf16x8 ah = *(const bf16x8*)(S + ((ks << 6) + lane) * 8);
        bf16x8 al = *(const bf16x8*)(S + 8192 + ((ks << 6) + lane) * 8);
#pragma unroll
        for (int i = 0; i < NFR; ++i) {
            acc[i] = __builtin_amdgcn_mfma_f32_16x16x32_bf16(ah, bh[slot][i], acc[i], 0, 0, 0);
            acc[i] = __builtin_amdgcn_mfma_f32_16x16x32_bf16(al, bh[slot][i], acc[i], 0, 0, 0);
            acc[i] = __builtin_amdgcn_mfma_f32_16x16x32_bf16(ah, bl[slot][i], acc[i], 0, 0, 0);
        }
        if (ks + DEPTH < KS) {
            const int p = ks + DEPTH;
#pragma unroll
            for (int i = 0; i < NFR; ++i) {
                bh[slot][i] = *(const bf16x8*)(base + ((i * KS + p) << 9));
                bl[slot][i] = *(const bf16x8*)(base + halfelems + ((i * KS + p) << 9));
            }
        }
    }
}

// Same, A-frags from registers (K=128 x-input), KS=4, full preload.
template<int NFR>
__device__ __forceinline__ void mm_x(const bf16* __restrict__ pk, int halfelems,
                                     int nf0, int lane,
                                     const bf16x8* xh, const bf16x8* xl, f32x4* acc)
{
    const int KS = 4;
    bf16x8 bh[4][NFR], bl[4][NFR];
    const bf16* base = pk + ((nf0 * KS) << 9) + (lane << 3);
#pragma unroll
    for (int p = 0; p < 4; ++p)
#pragma unroll
        for (int i = 0; i < NFR; ++i) {
            bh[p][i] = *(const bf16x8*)(base + ((i * KS + p) << 9));
            bl[p][i] = *(const bf16x8*)(base + halfelems + ((i * KS + p) << 9));
        }
#pragma unroll
    for (int i = 0; i < NFR; ++i) { f32x4 z = {0.f, 0.f, 0.f, 0.f}; acc[i] = z; }
#pragma unroll
    for (int ks = 0; ks < 4; ++ks)
#pragma unroll
        for (int i = 0; i < NFR; ++i) {
            acc[i] = __builtin_amdgcn_mfma_f32_16x16x32_bf16(xh[ks], bh[ks][i], acc[i], 0, 0, 0);
            acc[i] = __builtin_amdgcn_mfma_f32_16x16x32_bf16(xl[ks], bh[ks][i], acc[i], 0, 0, 0);
            acc[i] = __builtin_amdgcn_mfma_f32_16x16x32_bf16(xh[ks], bl[ks][i], acc[i], 0, 0, 0);
        }
}

// scatter one f32 value (tile row r in [0,16), col c in [0,512)) into split LDS S
__device__ __forceinline__ void scat(bf16* __restrict__ Sp, int r, int c, float v)
{
    bf16 hb = (bf16)v;
    bf16 lb = (bf16)(v - (float)hb);
    int off = (((c >> 5) << 6) + (r | (((c & 31) >> 3) << 4))) * 8 + (c & 7);
    Sp[off] = hb;
    Sp[8192 + off] = lb;
}

// ---------------------------------------------------------------------------
// Persistent kernel: 64 blocks x 512 threads (8 waves, 2/SIMD -> VGPR cap 512).
// Block owns 16 batch rows; wave owns 64 output cols (4 nf frags); h in LDS.
// ---------------------------------------------------------------------------
__global__ __launch_bounds__(512, 1)
void odegru_persist(const float* __restrict__ x, const float* __restrict__ t,
                    const float* __restrict__ bih, const float* __restrict__ bhh,
                    const float* __restrict__ b1,  const float* __restrict__ b2,
                    const float* __restrict__ bmu, const float* __restrict__ blv,
                    const bf16* __restrict__ pkW1, const bf16* __restrict__ pkW2,
                    const bf16* __restrict__ pkWhh, const bf16* __restrict__ pkWih,
                    const bf16* __restrict__ pkWout, float* __restrict__ out)
{
    __shared__ float hbuf[16 * 512];        // h, f32 [row][col]      (32 KB)
    __shared__ bf16  S[2 * 16 * 64 * 8];    // split operand buffer   (32 KB)

    const int tid  = threadIdx.x;
    const int lane = tid & 63;
    const int w    = tid >> 6;              // wave 0..7
    const int li   = lane & 15, lh = lane >> 4;
    const int m0   = blockIdx.x << 4;       // batch-row base
    const int Tn = 128, In = 128;

    const int c0 = (w << 6) + li;           // wave's first output col + lane col
    const int rb = lh << 2;                 // C-frag row base
    const int nf0 = w << 2;                 // wave's first N-frag (of 32)

    float b1c[4], b2c[4], bihr[4], bihz[4], bihn[4], bhhr[4], bhhz[4], bhhn[4];
#pragma unroll
    for (int fi = 0; fi < 4; ++fi) {
        int c = c0 + (fi << 4);
        b1c[fi] = b1[c];  b2c[fi] = b2[c];
        bihr[fi] = bih[c]; bihz[fi] = bih[512 + c]; bihn[fi] = bih[1024 + c];
        bhhr[fi] = bhh[c]; bhhz[fi] = bhh[512 + c]; bhhn[fi] = bhh[1024 + c];
    }

    f32x4 acc[4];
    float ksum[4][4];
    f32x4 gir[4], giz[4], gin[4], ghr[4], ghz[4], ghn[4];

    const int H1 = 32 * 16 * 512;   // halfelems pkW1/pkW2
    const int Hh = 96 * 16 * 512;   // pkWhh
    const int Hi = 96 * 4 * 512;    // pkWih
    const int Ho = 8 * 16 * 512;    // pkWout

    for (int s = 0; s < 128; ++s) {
        const float dt = (s > 0) ? (t[s] - t[s - 1]) : 0.f;
        if (s > 0) {
            const float a01 = dt * 0.125f, a2 = dt * 0.25f, hk = dt * (1.f / 24.f);
#pragma unroll 1
            for (int sub = 0; sub < 4; ++sub) {
#pragma unroll 1
                for (int st = 0; st < 4; ++st) {
                    // phase A: tmp_pre = A @ W1^T   (A-split in S)
                    mm_deep<4, 16, 6>(pkW1, H1, nf0, lane, S, acc);
                    __syncthreads();
                    // phase B: S = split(tanh(tmp_pre + b1))
#pragma unroll
                    for (int fi = 0; fi < 4; ++fi)
#pragma unroll
                        for (int rg = 0; rg < 4; ++rg)
                            scat(S, rb + rg, c0 + (fi << 4), tanhf(acc[fi][rg] + b1c[fi]));
                    __syncthreads();
                    // phase C: k = tmp @ W2^T
                    mm_deep<4, 16, 6>(pkW2, H1, nf0, lane, S, acc);
                    __syncthreads();
                    // phase D: RK4 combine; S = split(next A) or split(new h)
                    const float al = (st < 2) ? a01 : a2;
#pragma unroll
                    for (int fi = 0; fi < 4; ++fi)
#pragma unroll
                        for (int rg = 0; rg < 4; ++rg) {
                            float v = acc[fi][rg] + b2c[fi];
                            int c = c0 + (fi << 4);
                            int hoff = (rb + rg) * 512 + c;
                            if (st == 0) ksum[fi][rg] = v;
                            else if (st < 3) ksum[fi][rg] += 2.f * v;
                            float nv;
                            if (st < 3) {
                                nv = hbuf[hoff] + al * v;
                            } else {
                                nv = hbuf[hoff] + hk * (ksum[fi][rg] + v);
                                hbuf[hoff] = nv;
                            }
                            scat(S, rb + rg, c, nv);
                        }
                    __syncthreads();
                }
            }
        }
        // phase E: gi = x_s @ Wih^T  (x-frags in regs; r/z/n passes)
        bf16x8 xh[4], xl[4];
        {
            const float* xp = x + ((long)(m0 + li) * Tn + s) * In + (lh << 3);
#pragma unroll
            for (int ks = 0; ks < 4; ++ks) {
                f32x4 v0 = *(const f32x4*)(xp + (ks << 5));
                f32x4 v1 = *(const f32x4*)(xp + (ks << 5) + 4);
                bf16x8 h8, l8;
#pragma unroll
                for (int j = 0; j < 4; ++j) {
                    bf16 hb = (bf16)v0[j]; h8[j] = hb;     l8[j] = (bf16)(v0[j] - (float)hb);
                    bf16 h2 = (bf16)v1[j]; h8[4 + j] = h2; l8[4 + j] = (bf16)(v1[j] - (float)h2);
                }
                xh[ks] = h8; xl[ks] = l8;
            }
        }
        mm_x<4>(pkWih, Hi, nf0,      lane, xh, xl, gir);
        mm_x<4>(pkWih, Hi, 32 + nf0, lane, xh, xl, giz);
        mm_x<4>(pkWih, Hi, 64 + nf0, lane, xh, xl, gin);
        // phase F: gh = h @ Whh^T  (S still holds split(h)); r/z/n passes
        if (s > 0) {
            mm_deep<4, 16, 6>(pkWhh, Hh, nf0,      lane, S, ghr);
            mm_deep<4, 16, 6>(pkWhh, Hh, 32 + nf0, lane, S, ghz);
            mm_deep<4, 16, 6>(pkWhh, Hh, 64 + nf0, lane, S, ghn);
        } else {
#pragma unroll
            for (int i = 0; i < 4; ++i) {
                f32x4 z = {0.f, 0.f, 0.f, 0.f};
                ghr[i] = z; ghz[i] = z; ghn[i] = z;
            }
        }
        __syncthreads();
        // phase G: GRU gates; h <- (1-z)*n + z*h; S = split(h_new)
#pragma unroll
        for (int fi = 0; fi < 4; ++fi)
#pragma unroll
            for (int rg = 0; rg < 4; ++rg) {
                int c = c0 + (fi << 4);
                int hoff = (rb + rg) * 512 + c;
                float gr = gir[fi][rg] + bihr[fi] + ghr[fi][rg] + bhhr[fi];
                float gz = giz[fi][rg] + bihz[fi] + ghz[fi][rg] + bhhz[fi];
                float rr = 1.f / (1.f + __expf(-gr));
                float zz = 1.f / (1.f + __expf(-gz));
                float nn = tanhf(gin[fi][rg] + bihn[fi] + rr * (ghn[fi][rg] + bhhn[fi]));
                float hold = (s > 0) ? hbuf[hoff] : 0.f;
                float hn = (1.f - zz) * nn + zz * hold;
                hbuf[hoff] = hn;
                scat(S, rb + rg, c, hn);
            }
        __syncthreads();
    }
    // final: mu / logvar projections (S = split(h_T)); 8 waves x 1 nf = 128 cols
    {
        f32x4 oacc[1];
        mm_deep<1, 16, 6>(pkWout, Ho, w, lane, S, oacc);
        const float* bo = (w < 4) ? bmu : blv;
        int cl = ((w & 3) << 4) + li;
        float bv = bo[cl];
        float* ob = out + ((w < 4) ? 0 : 65536);
#pragma unroll
        for (int rg = 0; rg < 4; ++rg)
            ob[(long)(m0 + rb + rg) * 64 + cl] = oacc[0][rg] + bv;
    }
}

extern "C" void kernel_launch(void* const* d_in, const int* in_sizes, int n_in,
                              void* d_out, int out_size, void* d_ws, size_t ws_size,
                              hipStream_t stream)
{
    (void)in_sizes; (void)n_in; (void)out_size; (void)ws_size;
    const float* x   = (const float*)d_in[0];
    const float* t   = (const float*)d_in[1];
    const float* Wih = (const float*)d_in[2];
    const float* Whh = (const float*)d_in[3];
    const float* bih = (const float*)d_in[4];
    const float* bhh = (const float*)d_in[5];
    const float* W1  = (const float*)d_in[6];
    const float* b1  = (const float*)d_in[7];
    const float* W2  = (const float*)d_in[8];
    const float* b2  = (const float*)d_in[9];
    const float* Wmu = (const float*)d_in[10];
    const float* bmu = (const float*)d_in[11];
    const float* Wlv = (const float*)d_in[12];
    const float* blv = (const float*)d_in[13];
    float* out = (float*)d_out;

    bf16* pk1  = (bf16*)d_ws;             // 2*512*512   = 524288 elems (1 MB)
    bf16* pk2  = pk1 + 524288;            // 1 MB
    bf16* pkhh = pk2 + 524288;            // 2*1536*512  = 1572864 (3 MB)
    bf16* pkih = pkhh + 1572864;          // 2*1536*128  = 393216 (0.75 MB)
    bf16* pkout = pkih + 393216;          // 2*128*512   = 131072 (0.25 MB)

    pack_split<<<1024, 256, 0, stream>>>(W1,  pk1,  512, 512, 32, 0);
    pack_split<<<1024, 256, 0, stream>>>(W2,  pk2,  512, 512, 32, 0);
    pack_split<<<3072, 256, 0, stream>>>(Whh, pkhh, 1536, 512, 96, 0);
    pack_split<<<768,  256, 0, stream>>>(Wih, pkih, 1536, 128, 96, 0);
    pack_split<<<128,  256, 0, stream>>>(Wmu, pkout, 64, 512, 8, 0);
    pack_split<<<128,  256, 0, stream>>>(Wlv, pkout, 64, 512, 8, 4);

    odegru_persist<<<64, 512, 0, stream>>>(x, t, bih, bhh, b1, b2, bmu, blv,
                                           pk1, pk2, pkhh, pkih, pkout, out);
}

// Round 4
// 73381.946 us; speedup vs baseline: 3.0175x; 3.0175x over previous
//
#include <hip/hip_runtime.h>
#include <stdint.h>

typedef __bf16 bf16;
typedef __bf16 bf16x8 __attribute__((ext_vector_type(8)));
typedef float f32x4 __attribute__((ext_vector_type(4)));

#define SCOPE_AGENT __HIP_MEMORY_SCOPE_AGENT

// ---------------------------------------------------------------------------
// Weight pre-pack: f32 [N,K] row-major -> split hi/lo bf16 in MFMA B-frag
// streaming layout: pk[half][nf][ks][lane][8], lane=(n&15)|(((k&31)>>3)<<4),
// ks=k>>5, e=k&7.
// ---------------------------------------------------------------------------
__global__ void pack_split(const float* __restrict__ src, bf16* __restrict__ dst,
                           int N, int K, int NFtot, int nfBase)
{
    int gid = blockIdx.x * 256 + threadIdx.x;
    if (gid >= N * K) return;
    int n = gid / K, k = gid - n * K;
    int KS = K >> 5;
    float x = src[gid];
    bf16 hb = (bf16)x;                    // RNE
    bf16 lb = (bf16)(x - (float)hb);      // residual (exact in f32)
    int nf = nfBase + (n >> 4);
    int l  = (n & 15) | (((k & 31) >> 3) << 4);
    int ks = k >> 5;
    int e  = k & 7;
    int base = ((nf * KS + ks) << 9) + (l << 3) + e;
    int half = NFtot * KS * 512;
    dst[base] = hb;
    dst[half + base] = lb;
}

// swizzled elem offset of an 8-elem group in an S-style LDS buffer
__device__ __forceinline__ int soff(int ks, int ln) {
    return ((ks << 6) | (ln ^ (ks & 7))) << 3;
}

#define MFMA(a, b, c) __builtin_amdgcn_mfma_f32_16x16x32_bf16(a, b, c, 0, 0, 0)

// ---------------------------------------------------------------------------
// Cooperative persistent kernel: 256 blocks x 512 threads (8 waves), 1/CU.
// blockIdx = c*64 + g : row-group g (16 batch rows), col-part c (of 4).
// Siblings {g, g+64, g+128, g+192} share blockIdx%8 -> same XCD (perf only).
// Per f-eval: GEMM1 N-split -> local tmp slice; GEMM2 K-split -> partial k;
// publish partials; ONE sibling barrier; replicated RK4 combine rebuilds
// full-K split(A) in LDS. GRU: gates col-split, one h-exchange barrier/step.
// ---------------------------------------------------------------------------
__global__ __launch_bounds__(512, 2)
void odegru_coop(const float* __restrict__ x, const float* __restrict__ t,
                 const float* __restrict__ bih, const float* __restrict__ bhh,
                 const float* __restrict__ b1,  const float* __restrict__ b2,
                 const float* __restrict__ bmu, const float* __restrict__ blv,
                 const bf16* __restrict__ pkW1, const bf16* __restrict__ pkW2,
                 const bf16* __restrict__ pkWhh, const bf16* __restrict__ pkWih,
                 const bf16* __restrict__ pkWout,
                 float* __restrict__ kpart, float* __restrict__ hex,
                 unsigned int* __restrict__ cnt, float* __restrict__ out)
{
    __shared__ __align__(16) bf16 S[2 * 8192];    // split(A/h), K=512 (32 KB)
    __shared__ __align__(16) bf16 S2[2 * 2048];   // split(tmp slice), K=128 (8 KB)
    __shared__ float hstage[16 * 128];            // own-col h f32 (8 KB)

    const int tid  = threadIdx.x;
    const int lane = tid & 63;
    const int w    = tid >> 6;            // wave 0..7
    const int li   = lane & 15, lh = lane >> 4;
    const int bid  = blockIdx.x;
    const int g    = bid & 63;            // row group
    const int c    = bid >> 6;            // col part 0..3
    const int m0   = g << 4;

    // D-phase ownership: row dr, 16 cols starting dn0
    const int dr  = tid >> 5;
    const int dn0 = (tid & 31) << 4;

    const int H1 = 32 * 16 * 512;
    const int Hh = 96 * 16 * 512;
    const int Hi = 96 * 4 * 512;
    const int Ho = 8 * 16 * 512;

    // per-wave preloads (own GEMM/gate column cg)
    const int cg = c * 128 + w * 16 + li;
    const float b1v = b1[cg];
    const float bir = bih[cg], biz = bih[512 + cg], bin_ = bih[1024 + cg];
    const float bhr = bhh[cg], bhz = bhh[512 + cg], bhn = bhh[1024 + cg];
    f32x4 b2r[4];
#pragma unroll
    for (int j = 0; j < 4; ++j) b2r[j] = *(const f32x4*)(b2 + dn0 + 4 * j);

    f32x4 h4[4];    // D-thread replicated h (16 f32)
    f32x4 ks4[4];   // RK4 ksum
    int ep = 0;
    int fe = 0;     // f-eval counter (kpart double-buffer parity)
    unsigned int* myc = cnt + g * 64;

    for (int s = 0; s < 128; ++s) {
        const float dt = (s > 0) ? (t[s] - t[s - 1]) : 0.f;
        if (s > 0) {
            const float a01 = dt * 0.125f, a2c = dt * 0.25f, hk = dt * (1.f / 24.f);
#pragma unroll 1
            for (int sub = 0; sub < 4; ++sub) {
#pragma unroll 1
                for (int st = 0; st < 4; ++st) {
                    // ---- GEMM1 (N-split): tmp_pre = A @ W1^T, own 128 cols
                    {
                        f32x4 a1 = {0.f, 0.f, 0.f, 0.f};
                        const bf16* pb = pkW1 + (((c * 8 + w) * 16) << 9) + (lane << 3);
#pragma unroll
                        for (int ks = 0; ks < 16; ++ks) {
                            bf16x8 ah = *(const bf16x8*)(S + soff(ks, lane));
                            bf16x8 al = *(const bf16x8*)(S + 8192 + soff(ks, lane));
                            bf16x8 bh = *(const bf16x8*)(pb + (ks << 9));
                            bf16x8 bl = *(const bf16x8*)(pb + H1 + (ks << 9));
                            a1 = MFMA(ah, bh, a1);
                            a1 = MFMA(al, bh, a1);
                            a1 = MFMA(ah, bl, a1);
                        }
                        // epilogue: tanh -> scat into S2 (local col = w*16+li)
#pragma unroll
                        for (int rg = 0; rg < 4; ++rg) {
                            float v = tanhf(a1[rg] + b1v);
                            int r = lh * 4 + rg, n = w * 16 + li;
                            int ks = n >> 5, ln = r | (((n & 31) >> 3) << 4);
                            int off = (((ks << 6) | (ln ^ (ks & 7))) << 3) + (n & 7);
                            bf16 hb = (bf16)v;
                            S2[off] = hb;
                            S2[2048 + off] = (bf16)(v - (float)hb);
                        }
                    }
                    __syncthreads();
                    // ---- GEMM2 (K-split): partial k = tmp_slice @ W2^T (all 512 cols)
                    {
                        f32x4 a2[4];
#pragma unroll
                        for (int j = 0; j < 4; ++j) { f32x4 z = {0.f, 0.f, 0.f, 0.f}; a2[j] = z; }
#pragma unroll
                        for (int kk = 0; kk < 4; ++kk) {
                            bf16x8 ah = *(const bf16x8*)(S2 + soff(kk, lane));
                            bf16x8 al = *(const bf16x8*)(S2 + 2048 + soff(kk, lane));
#pragma unroll
                            for (int j = 0; j < 4; ++j) {
                                const bf16* pb = pkW2 + ((((w + 8 * j) * 16 + c * 4 + kk)) << 9) + (lane << 3);
                                bf16x8 bh = *(const bf16x8*)pb;
                                bf16x8 bl = *(const bf16x8*)(pb + H1);
                                a2[j] = MFMA(ah, bh, a2[j]);
                                a2[j] = MFMA(al, bh, a2[j]);
                                a2[j] = MFMA(ah, bl, a2[j]);
                            }
                        }
                        // publish partial k (row,col)-major f32
                        float* kp = kpart + ((size_t)((fe & 1) * 256 + g * 4 + c) << 13);
#pragma unroll
                        for (int j = 0; j < 4; ++j)
#pragma unroll
                            for (int rg = 0; rg < 4; ++rg)
                                kp[(lh * 4 + rg) * 512 + (w + 8 * j) * 16 + li] = a2[j][rg];
                    }
                    // ---- sibling barrier (release publish / acquire partials)
                    ++ep;
                    __syncthreads();
                    if (tid == 0) {
                        __hip_atomic_fetch_add(myc, 1u, __ATOMIC_RELEASE, SCOPE_AGENT);
                        unsigned int tgt = 4u * (unsigned int)ep;
                        while (__hip_atomic_load(myc, __ATOMIC_ACQUIRE, SCOPE_AGENT) < tgt)
                            __builtin_amdgcn_s_sleep(4);
                    }
                    __syncthreads();
                    // ---- replicated RK4 combine (D): full-K next-A into S
                    {
                        f32x4 vsum[4];
#pragma unroll
                        for (int j = 0; j < 4; ++j) vsum[j] = b2r[j];
#pragma unroll
                        for (int cc = 0; cc < 4; ++cc) {
                            const float* kq = kpart + ((size_t)((fe & 1) * 256 + g * 4 + cc) << 13)
                                              + dr * 512 + dn0;
#pragma unroll
                            for (int j = 0; j < 4; ++j) vsum[j] += *(const f32x4*)(kq + 4 * j);
                        }
                        f32x4 An[4];
                        if (st == 0) {
#pragma unroll
                            for (int j = 0; j < 4; ++j) ks4[j] = vsum[j];
                        } else if (st < 3) {
#pragma unroll
                            for (int j = 0; j < 4; ++j) ks4[j] += 2.f * vsum[j];
                        }
                        if (st < 3) {
                            const float alc = (st < 2) ? a01 : a2c;
#pragma unroll
                            for (int j = 0; j < 4; ++j) An[j] = h4[j] + alc * vsum[j];
                        } else {
#pragma unroll
                            for (int j = 0; j < 4; ++j) { h4[j] = h4[j] + hk * (ks4[j] + vsum[j]); An[j] = h4[j]; }
                        }
                        // vectorized split-scat into S (2 chunks of 8 cols)
#pragma unroll
                        for (int ch = 0; ch < 2; ++ch) {
                            int n = dn0 + ch * 8;
                            int ks = n >> 5, ln = dr | (((n & 31) >> 3) << 4);
                            int off = ((ks << 6) | (ln ^ (ks & 7))) << 3;
                            bf16x8 hv, lv;
#pragma unroll
                            for (int e = 0; e < 8; ++e) {
                                float vv = An[ch * 2 + (e >> 2)][e & 3];
                                bf16 hb = (bf16)vv;
                                hv[e] = hb;
                                lv[e] = (bf16)(vv - (float)hb);
                            }
                            *(bf16x8*)(S + off) = hv;
                            *(bf16x8*)(S + 8192 + off) = lv;
                        }
                        if (st == 3 && sub == 3 && (dn0 >> 7) == c) {
#pragma unroll
                            for (int j = 0; j < 4; ++j)
                                *(f32x4*)(hstage + dr * 128 + (dn0 & 127) + 4 * j) = h4[j];
                        }
                    }
                    __syncthreads();
                    ++fe;
                }
            }
        }
        // ---- GRU: gi (x from regs) + gh (h from S), gates col-split
        f32x4 gr, gz, gn2, hr, hz, hn2;
        {
            bf16x8 xh[4], xl[4];
            const float* xp = x + ((size_t)(m0 + li) * 128 + s) * 128 + (lh << 3);
#pragma unroll
            for (int ks = 0; ks < 4; ++ks) {
                f32x4 v0 = *(const f32x4*)(xp + (ks << 5));
                f32x4 v1 = *(const f32x4*)(xp + (ks << 5) + 4);
                bf16x8 h8, l8;
#pragma unroll
                for (int j = 0; j < 4; ++j) {
                    bf16 hb = (bf16)v0[j]; h8[j] = hb;     l8[j] = (bf16)(v0[j] - (float)hb);
                    bf16 h2 = (bf16)v1[j]; h8[4 + j] = h2; l8[4 + j] = (bf16)(v1[j] - (float)h2);
                }
                xh[ks] = h8; xl[ks] = l8;
            }
            f32x4 z4 = {0.f, 0.f, 0.f, 0.f};
            gr = z4; gz = z4; gn2 = z4;
#pragma unroll
            for (int ks = 0; ks < 4; ++ks) {
#pragma unroll
                for (int gate = 0; gate < 3; ++gate) {
                    const bf16* pb = pkWih + (((32 * gate + 8 * c + w) * 4 + ks) << 9) + (lane << 3);
                    bf16x8 bh = *(const bf16x8*)pb;
                    bf16x8 bl = *(const bf16x8*)(pb + Hi);
                    f32x4 acc = (gate == 0) ? gr : (gate == 1) ? gz : gn2;
                    acc = MFMA(xh[ks], bh, acc);
                    acc = MFMA(xl[ks], bh, acc);
                    acc = MFMA(xh[ks], bl, acc);
                    if (gate == 0) gr = acc; else if (gate == 1) gz = acc; else gn2 = acc;
                }
            }
            f32x4 z5 = {0.f, 0.f, 0.f, 0.f};
            hr = z5; hz = z5; hn2 = z5;
            if (s > 0) {
#pragma unroll
                for (int ks = 0; ks < 16; ++ks) {
                    bf16x8 ah = *(const bf16x8*)(S + soff(ks, lane));
                    bf16x8 al = *(const bf16x8*)(S + 8192 + soff(ks, lane));
#pragma unroll
                    for (int gate = 0; gate < 3; ++gate) {
                        const bf16* pb = pkWhh + (((32 * gate + 8 * c + w) * 16 + ks) << 9) + (lane << 3);
                        bf16x8 bh = *(const bf16x8*)pb;
                        bf16x8 bl = *(const bf16x8*)(pb + Hh);
                        f32x4 acc = (gate == 0) ? hr : (gate == 1) ? hz : hn2;
                        acc = MFMA(ah, bh, acc);
                        acc = MFMA(al, bh, acc);
                        acc = MFMA(ah, bl, acc);
                        if (gate == 0) hr = acc; else if (gate == 1) hz = acc; else hn2 = acc;
                    }
                }
            }
        }
        // gates -> h_new own cols -> publish
        {
            float* hx = hex + ((size_t)(g * 4 + c)) * 2048;
#pragma unroll
            for (int rg = 0; rg < 4; ++rg) {
                float r_ = 1.f / (1.f + __expf(-(gr[rg] + bir + hr[rg] + bhr)));
                float z_ = 1.f / (1.f + __expf(-(gz[rg] + biz + hz[rg] + bhz)));
                float n_ = tanhf(gn2[rg] + bin_ + r_ * (hn2[rg] + bhn));
                float hold = (s > 0) ? hstage[(lh * 4 + rg) * 128 + w * 16 + li] : 0.f;
                hx[(lh * 4 + rg) * 128 + w * 16 + li] = (1.f - z_) * n_ + z_ * hold;
            }
        }
        ++ep;
        __syncthreads();
        if (tid == 0) {
            __hip_atomic_fetch_add(myc, 1u, __ATOMIC_RELEASE, SCOPE_AGENT);
            unsigned int tgt = 4u * (unsigned int)ep;
            while (__hip_atomic_load(myc, __ATOMIC_ACQUIRE, SCOPE_AGENT) < tgt)
                __builtin_amdgcn_s_sleep(4);
        }
        __syncthreads();
        // replicate h_new into D regs + S
        {
            const float* hq = hex + ((size_t)(g * 4 + (dn0 >> 7))) * 2048 + dr * 128 + (dn0 & 127);
#pragma unroll
            for (int j = 0; j < 4; ++j) h4[j] = *(const f32x4*)(hq + 4 * j);
#pragma unroll
            for (int ch = 0; ch < 2; ++ch) {
                int n = dn0 + ch * 8;
                int ks = n >> 5, ln = dr | (((n & 31) >> 3) << 4);
                int off = ((ks << 6) | (ln ^ (ks & 7))) << 3;
                bf16x8 hv, lv;
#pragma unroll
                for (int e = 0; e < 8; ++e) {
                    float vv = h4[ch * 2 + (e >> 2)][e & 3];
                    bf16 hb = (bf16)vv;
                    hv[e] = hb;
                    lv[e] = (bf16)(vv - (float)hb);
                }
                *(bf16x8*)(S + off) = hv;
                *(bf16x8*)(S + 8192 + off) = lv;
            }
        }
        __syncthreads();
    }
    // ---- mu / logvar projections: block computes out frags {2c, 2c+1}
    if (w < 2) {
        const int nfo = 2 * c + w;
        f32x4 ao = {0.f, 0.f, 0.f, 0.f};
        const bf16* pb = pkWout + ((nfo * 16) << 9) + (lane << 3);
#pragma unroll
        for (int ks = 0; ks < 16; ++ks) {
            bf16x8 ah = *(const bf16x8*)(S + soff(ks, lane));
            bf16x8 al = *(const bf16x8*)(S + 8192 + soff(ks, lane));
            bf16x8 bh = *(const bf16x8*)(pb + (ks << 9));
            bf16x8 bl = *(const bf16x8*)(pb + Ho + (ks << 9));
            ao = MFMA(ah, bh, ao);
            ao = MFMA(al, bh, ao);
            ao = MFMA(ah, bl, ao);
        }
        const float* bo = (nfo < 4) ? bmu : blv;
        int col = (nfo & 3) * 16 + li;
        float bv = bo[col];
        float* op = out + ((nfo < 4) ? 0 : 65536);
#pragma unroll
        for (int rg = 0; rg < 4; ++rg)
            op[(size_t)(m0 + lh * 4 + rg) * 64 + col] = ao[rg] + bv;
    }
}

extern "C" void kernel_launch(void* const* d_in, const int* in_sizes, int n_in,
                              void* d_out, int out_size, void* d_ws, size_t ws_size,
                              hipStream_t stream)
{
    (void)in_sizes; (void)n_in; (void)out_size; (void)ws_size;
    const float* x   = (const float*)d_in[0];
    const float* t   = (const float*)d_in[1];
    const float* Wih = (const float*)d_in[2];
    const float* Whh = (const float*)d_in[3];
    const float* bih = (const float*)d_in[4];
    const float* bhh = (const float*)d_in[5];
    const float* W1  = (const float*)d_in[6];
    const float* b1  = (const float*)d_in[7];
    const float* W2  = (const float*)d_in[8];
    const float* b2  = (const float*)d_in[9];
    const float* Wmu = (const float*)d_in[10];
    const float* bmu = (const float*)d_in[11];
    const float* Wlv = (const float*)d_in[12];
    const float* blv = (const float*)d_in[13];
    float* out = (float*)d_out;

    char* wsb = (char*)d_ws;
    unsigned int* cnt = (unsigned int*)wsb;                 // 16 KB (64 groups x 256B)
    float* kpart = (float*)(wsb + (64l << 10));             // 16 MB: 2 x 256 x 8192 f32
    float* hex   = (float*)(wsb + (64l << 10) + (16l << 20)); // 2 MB
    bf16* pk1   = (bf16*)(wsb + (64l << 10) + (18l << 20)); // 1 MB
    bf16* pk2   = pk1 + 524288;                             // 1 MB
    bf16* pkhh  = pk2 + 524288;                             // 3 MB
    bf16* pkih  = pkhh + 1572864;                           // 0.75 MB
    bf16* pkout = pkih + 393216;                            // 0.25 MB

    hipMemsetAsync(cnt, 0, 64 * 256, stream);

    pack_split<<<1024, 256, 0, stream>>>(W1,  pk1,  512, 512, 32, 0);
    pack_split<<<1024, 256, 0, stream>>>(W2,  pk2,  512, 512, 32, 0);
    pack_split<<<3072, 256, 0, stream>>>(Whh, pkhh, 1536, 512, 96, 0);
    pack_split<<<768,  256, 0, stream>>>(Wih, pkih, 1536, 128, 96, 0);
    pack_split<<<128,  256, 0, stream>>>(Wmu, pkout, 64, 512, 8, 0);
    pack_split<<<128,  256, 0, stream>>>(Wlv, pkout, 64, 512, 8, 4);

    odegru_coop<<<256, 512, 0, stream>>>(x, t, bih, bhh, b1, b2, bmu, blv,
                                         pk1, pk2, pkhh, pkih, pkout,
                                         kpart, hex, cnt, out);
}